// Round 4
// baseline (58.957 us; speedup 1.0000x reference)
//
#include <hip/hip_runtime.h>
#include <math.h>

#define NB 128
#define NC 8
#define NV 16384
#define NK 64
#define NR 128

// flat output offsets (elements, f32)
#define OFF_MASKS  0
#define OFF_VP     2097152
#define OFF_THETAS 8388608
#define OFF_ALPHAS 8388736
#define OFF_ROT    8388864
#define OFF_SCALES 8389376
#define OFF_DEPTHS 8389504
#define OFF_C2D    8389632
#define OFF_TRANS  8389888
#define OFF_CLP    8390272

#define PI_F     3.14159265358979323846f
#define TWOPI_F  6.28318530717958647692f

// d_ws layout (Wi = int view, Wf = float view), 104,192 bytes total:
//   Wi[0..31]      group class (-1 = invalid group)
//   Wi[32..63]     group slot base (into T)
//   Wi[64..319]    T[256]: slot -> record (class-padded to multiples of 8)
//   Wi[320..447]   record -> batch id
//   Wf[448+r*8]    params per record: scale,qw,qy,tx,ty,tz,feff,pad
//   Wf[1472+r*192] coeffs per record (K=64 x 3)

__device__ __forceinline__ float rflf(float x) {
  return __int_as_float(__builtin_amdgcn_readfirstlane(__float_as_int(x)));
}

// ---- kernel 1: zero masks (grid-wide); block 0: scalars + padded work queue -
__global__ __launch_bounds__(256) void prep_kernel(
    const float* __restrict__ roi, const float* __restrict__ focals,
    const float* __restrict__ td,  const float* __restrict__ t2,
    const float* __restrict__ ls,  const float* __restrict__ ld,
    const float* __restrict__ cp,  const float* __restrict__ fc,
    float* __restrict__ out, int* __restrict__ Wi, float* __restrict__ Wf) {
  int tid = threadIdx.x;
  int i = blockIdx.x * 256 + tid;
  float4 z; z.x = 0.0f; z.y = 0.0f; z.z = 0.0f; z.w = 0.0f;
  ((float4*)(out + OFF_MASKS))[i] = z;   // 2048*256 float4 = whole mask region
  if (blockIdx.x != 0) return;

  __shared__ int cls_sh[NB];
  __shared__ int scnt[NC + 1];
  int b = tid;
  float scale = 0, qw = 0, qy = 0, tx_ = 0, ty_ = 0, tz_ = 0, feff = 0;
  int cls = 0;
  if (b < NB) {
    float r0 = roi[b * 4 + 0], r1 = roi[b * 4 + 1];
    float r2 = roi[b * 4 + 2], r3 = roi[b * 4 + 3];
    float dx = r2 - r0, dy = r3 - r1;
    float mx = 0.5f * (r2 + r0), my = 0.5f * (r3 + r1);
    float theta = atan2f(td[b * 2 + 1], td[b * 2 + 0]);
    qw = cosf(0.5f * theta);
    qy = sinf(0.5f * theta);
    float area  = dx * dy;
    scale = expf(ls[b]);
    float depth = sqrtf(expf(ld[b]) / area);
    float cx = mx + t2[b * 2 + 0] * dx;
    float cy = my + t2[b * 2 + 1] * dy;
    float tux = cy, tuy = -cx;
    float n = sqrtf(tux * tux + tuy * tuy + 1.0f);
    tx_ = depth * (tux / n);
    ty_ = depth * (tuy / n);
    tz_ = depth * (-1.0f / n);
    float alpha = -(theta - atanf(tx_ / tz_));
    float a  = alpha + PI_F;
    float rr = fmodf(a, TWOPI_F);
    if (rr < 0.0f) rr += TWOPI_F;
    float alpha_out = rr - PI_F;
    float pmax = cp[b * NC];
    for (int c = 1; c < NC; ++c) {
      float pv = cp[b * NC + c];
      if (pv > pmax) { pmax = pv; cls = c; }
    }
    feff = 2.0f * focals[b] / (float)NR;

    out[OFF_THETAS + b]      = theta;
    out[OFF_ALPHAS + b]      = alpha_out;
    out[OFF_ROT + 4 * b + 0] = qw;
    out[OFF_ROT + 4 * b + 1] = 0.0f;
    out[OFF_ROT + 4 * b + 2] = qy;
    out[OFF_ROT + 4 * b + 3] = 0.0f;
    out[OFF_SCALES + b]      = scale;
    out[OFF_DEPTHS + b]      = depth;
    out[OFF_C2D + 2 * b + 0] = cx;
    out[OFF_C2D + 2 * b + 1] = cy;
    out[OFF_TRANS + 3 * b + 0] = tx_;
    out[OFF_TRANS + 3 * b + 1] = ty_;
    out[OFF_TRANS + 3 * b + 2] = tz_;
    out[OFF_CLP + b]         = logf(pmax);
    cls_sh[b] = cls;
  }
  __syncthreads();
  if (tid <= NC) {
    int cnt = 0;
    for (int j = 0; j < NB; ++j) cnt += (cls_sh[j] < tid);
    scnt[tid] = cnt;
  }
  __syncthreads();
  if (b < NB) {
    // stable counting-sort rank by (class, batch)
    int rank = scnt[cls];
    for (int j = 0; j < b; ++j) rank += (cls_sh[j] == cls);
    Wi[320 + rank] = b;
    float* par = Wf + 448 + rank * 8;
    par[0] = scale; par[1] = qw; par[2] = qy; par[3] = tx_;
    par[4] = ty_;   par[5] = tz_; par[6] = feff; par[7] = 0.0f;
    const float4* src = (const float4*)(fc + ((size_t)(b * NC + cls)) * 192);
    float4* dst = (float4*)(Wf + 1472 + (size_t)rank * 192);
#pragma unroll 8
    for (int t = 0; t < 48; ++t) dst[t] = src[t];
  }
  if (tid == 0) {
    int gi = 0, tpos = 0;
    for (int c = 0; c < NC; ++c) {
      int n  = scnt[c + 1] - scnt[c];
      int ng = (n + 7) >> 3;
      for (int k = 0; k < ng; ++k) {
        Wi[gi] = c;
        Wi[32 + gi] = tpos;
        for (int s = 0; s < 8; ++s) {
          int idx = k * 8 + s;
          Wi[64 + tpos + s] = scnt[c] + ((idx < n) ? idx : 0);  // pad: dup first
        }
        tpos += 8;
        ++gi;
      }
    }
    for (; gi < 32; ++gi) { Wi[gi] = -1; Wi[32 + gi] = 0; }
    for (; tpos < 256; ++tpos) Wi[64 + tpos] = 0;
  }
}

// ---- kernel 2: chunk-outer FFD + transform + project + scatter --------------
// grid (64 tiles, 32 groups). One block = one v-tile x one 8-slot group.
// One basis float4 load feeds 8 slots x 12 FMAs; acc[8][3] lives in VGPRs.
__global__ __launch_bounds__(256) void verts_kernel(
    const float* __restrict__ basev,    // (C, V, 3)
    const float* __restrict__ basis,    // (C, V, K)
    const int*   __restrict__ Wi,
    const float* __restrict__ Wf,
    float* __restrict__ out) {
  int g   = blockIdx.y;
  int myc = Wi[g];
  if (myc < 0) return;
  int base = Wi[32 + g];
  int v = blockIdx.x * 256 + threadIdx.x;

  int rr_[8], bb_[8];
#pragma unroll
  for (int s = 0; s < 8; ++s) {
    rr_[s] = __builtin_amdgcn_readfirstlane(Wi[64 + base + s]);
    bb_[s] = __builtin_amdgcn_readfirstlane(Wi[320 + rr_[s]]);
  }
  const float4* cp_[8];
#pragma unroll
  for (int s = 0; s < 8; ++s)
    cp_[s] = (const float4*)(Wf + 1472 + (size_t)rr_[s] * 192);

  const float4* brow = (const float4*)(basis + ((size_t)myc * NV + v) * NK);
  const float*  bp   = basev + ((size_t)myc * NV + v) * 3;
  float bpx = bp[0], bpy = bp[1], bpz = bp[2];

  float ax[8], ay[8], az[8];
#pragma unroll
  for (int s = 0; s < 8; ++s) { ax[s] = 0.0f; ay[s] = 0.0f; az[s] = 0.0f; }

  float4 bv = brow[0];
#pragma unroll 4
  for (int ch = 0; ch < 16; ++ch) {
    int nc = (ch < 15) ? ch + 1 : 15;
    float4 bn = brow[nc];            // prefetch (last chunk re-reads itself)
#pragma unroll
    for (int s = 0; s < 8; ++s) {
      float4 c0 = cp_[s][3 * ch + 0];
      float4 c1 = cp_[s][3 * ch + 1];
      float4 c2 = cp_[s][3 * ch + 2];
      ax[s] = fmaf(bv.x, c0.x, ax[s]);
      ay[s] = fmaf(bv.x, c0.y, ay[s]);
      az[s] = fmaf(bv.x, c0.z, az[s]);
      ax[s] = fmaf(bv.y, c0.w, ax[s]);
      ay[s] = fmaf(bv.y, c1.x, ay[s]);
      az[s] = fmaf(bv.y, c1.y, az[s]);
      ax[s] = fmaf(bv.z, c1.z, ax[s]);
      ay[s] = fmaf(bv.z, c1.w, ay[s]);
      az[s] = fmaf(bv.z, c2.x, az[s]);
      ax[s] = fmaf(bv.w, c2.y, ax[s]);
      ay[s] = fmaf(bv.w, c2.z, ay[s]);
      az[s] = fmaf(bv.w, c2.w, az[s]);
    }
    bv = bn;
  }

#pragma unroll
  for (int s = 0; s < 8; ++s) {
    const float* pp = Wf + 448 + rr_[s] * 8;
    float scale = rflf(pp[0]);
    float qw    = rflf(pp[1]);
    float qy    = rflf(pp[2]);
    float tx    = rflf(pp[3]);
    float ty    = rflf(pp[4]);
    float tz    = rflf(pp[5]);
    float feff  = rflf(pp[6]);
    int   b     = bb_[s];

    float vx = (bpx + ax[s]) * scale;
    float vy = (bpy + ay[s]) * scale;
    float vz = (bpz + az[s]) * scale;
    float t2x = 2.0f * qy * vz;
    float t2z = -2.0f * qy * vx;
    float rx = vx + qw * t2x + qy * t2z;
    float ry = vy;
    float rz = vz + qw * t2z - qy * t2x;
    float wx = rx + tx, wy = ry + ty, wz = rz + tz;

    float zv = wz;
    float zsafe = (zv > -1e-4f) ? -1e-4f : zv;
    float inv = feff / (-zsafe);
    float u  = wx * inv;
    float vv = wy * inv;
    float px = (u * 0.5f + 0.5f) * (float)NR;
    float py = (vv * 0.5f + 0.5f) * (float)NR;

    float* o = out + OFF_VP + (size_t)(b * NV + v) * 3;
    o[0] = px; o[1] = py; o[2] = -zv;

    int xi = (int)fminf(fmaxf(px, 0.0f), 127.0f);
    int yi = (int)fminf(fmaxf(py, 0.0f), 127.0f);
    out[OFF_MASKS + (b << 14) + yi * NR + xi] = 1.0f;
  }
}

extern "C" void kernel_launch(void* const* d_in, const int* in_sizes, int n_in,
                              void* d_out, int out_size, void* d_ws, size_t ws_size,
                              hipStream_t stream) {
  const float* roi    = (const float*)d_in[0];
  const float* focals = (const float*)d_in[1];
  const float* td     = (const float*)d_in[2];
  const float* t2     = (const float*)d_in[3];
  const float* ls     = (const float*)d_in[4];
  const float* ld     = (const float*)d_in[5];
  const float* cp     = (const float*)d_in[6];
  const float* fc     = (const float*)d_in[7];
  const float* bv     = (const float*)d_in[8];
  const float* fb     = (const float*)d_in[9];
  float* out = (float*)d_out;
  int*   Wi  = (int*)d_ws;
  float* Wf  = (float*)d_ws;

  prep_kernel<<<dim3(2048), dim3(256), 0, stream>>>(
      roi, focals, td, t2, ls, ld, cp, fc, out, Wi, Wf);
  verts_kernel<<<dim3(64, 32), dim3(256), 0, stream>>>(
      bv, fb, Wi, Wf, out);
}

// Round 5
// 44.183 us; speedup vs baseline: 1.3344x; 1.3344x over previous
//
#include <hip/hip_runtime.h>
#include <math.h>

#define NB 128
#define NC 8
#define NV 16384
#define NK 64
#define NR 128

// flat output offsets (elements, f32)
#define OFF_MASKS  0
#define OFF_VP     2097152
#define OFF_THETAS 8388608
#define OFF_ALPHAS 8388736
#define OFF_ROT    8388864
#define OFF_SCALES 8389376
#define OFF_DEPTHS 8389504
#define OFF_C2D    8389632
#define OFF_TRANS  8389888
#define OFF_CLP    8390272

#define PI_F     3.14159265358979323846f
#define TWOPI_F  6.28318530717958647692f

// d_ws layout:
//   Wi[0..8]        scnt: class prefix over records
//   Wi[16..24]      cts:  class prefix over col-tiles (ceil(n_c/5) each)
//   Wi[32+r]        record -> batch id (class-sorted, r = 0..127)
//   Wf[256+r*8]     params per record: scale,qw,qy,tx,ty,tz,feff,pad
//   Wf[1280...]     Bpack (ushort): per (coltile t, kstep ks): 512 bf16
//                   element (t*2+ks)*512 + lane*8 + j  <->  B[col=lane&15][k=ks*32+(lane>>4)*8+j]
//                   max 33 coltiles -> 33*1024 ushort = 66 KB; total ws ~72 KB

typedef short  short8 __attribute__((ext_vector_type(8)));
typedef float  f32x4  __attribute__((ext_vector_type(4)));

__device__ __forceinline__ unsigned short f2bf(float f) {
  unsigned int u = __float_as_uint(f);
  unsigned int r = (u + 0x7FFFu + ((u >> 16) & 1u)) >> 16;   // RNE
  return (unsigned short)r;
}

// ---- kernel 1: zero masks (all blocks); blocks 0..16: tables + B-pack -------
__global__ __launch_bounds__(256) void prep_kernel(
    const float* __restrict__ roi, const float* __restrict__ focals,
    const float* __restrict__ td,  const float* __restrict__ t2,
    const float* __restrict__ ls,  const float* __restrict__ ld,
    const float* __restrict__ cp,  const float* __restrict__ fc,
    float* __restrict__ out, int* __restrict__ Wi, float* __restrict__ Wf) {
  int tid = threadIdx.x;
  int bx  = blockIdx.x;
  {
    int i = bx * 256 + tid;
    float4 z; z.x = 0.0f; z.y = 0.0f; z.z = 0.0f; z.w = 0.0f;
    ((float4*)(out + OFF_MASKS))[i] = z;   // 2048*256 float4 = whole mask region
  }
  if (bx > 16) return;

  __shared__ int cls_sh[NB];
  __shared__ int rb_sh[NB];
  __shared__ int scnt_sh[NC + 1];
  __shared__ int cts_sh[NC + 1];

  int b = tid;
  int cls = 0;
  if (b < NB) {
    float pmax = cp[b * NC];
    for (int c = 1; c < NC; ++c) {
      float pv = cp[b * NC + c];
      if (pv > pmax) { pmax = pv; cls = c; }
    }
    cls_sh[b] = cls;
  }
  __syncthreads();
  if (tid <= NC) {
    int cnt = 0;
    for (int j = 0; j < NB; ++j) cnt += (cls_sh[j] < tid);
    scnt_sh[tid] = cnt;
  }
  __syncthreads();
  if (tid == 0) {
    cts_sh[0] = 0;
    for (int c = 0; c < NC; ++c) {
      int n = scnt_sh[c + 1] - scnt_sh[c];
      cts_sh[c + 1] = cts_sh[c] + (n + 4) / 5;
    }
  }
  int rank = 0;
  if (b < NB) {
    rank = scnt_sh[cls];
    for (int j = 0; j < b; ++j) rank += (cls_sh[j] == cls);
    rb_sh[rank] = b;
  }
  __syncthreads();

  if (bx == 0) {
    // scalar outputs + tables + params
    if (b < NB) {
      float r0 = roi[b * 4 + 0], r1 = roi[b * 4 + 1];
      float r2 = roi[b * 4 + 2], r3 = roi[b * 4 + 3];
      float dx = r2 - r0, dy = r3 - r1;
      float mx = 0.5f * (r2 + r0), my = 0.5f * (r3 + r1);
      float theta = atan2f(td[b * 2 + 1], td[b * 2 + 0]);
      float qw = cosf(0.5f * theta);
      float qy = sinf(0.5f * theta);
      float area  = dx * dy;
      float scale = expf(ls[b]);
      float depth = sqrtf(expf(ld[b]) / area);
      float cx = mx + t2[b * 2 + 0] * dx;
      float cy = my + t2[b * 2 + 1] * dy;
      float tux = cy, tuy = -cx;
      float n = sqrtf(tux * tux + tuy * tuy + 1.0f);
      float tx_ = depth * (tux / n);
      float ty_ = depth * (tuy / n);
      float tz_ = depth * (-1.0f / n);
      float alpha = -(theta - atanf(tx_ / tz_));
      float a  = alpha + PI_F;
      float rr = fmodf(a, TWOPI_F);
      if (rr < 0.0f) rr += TWOPI_F;
      float alpha_out = rr - PI_F;
      float pmax = cp[b * NC];
      for (int c = 1; c < NC; ++c) pmax = fmaxf(pmax, cp[b * NC + c]);
      float feff = 2.0f * focals[b] / (float)NR;

      out[OFF_THETAS + b]      = theta;
      out[OFF_ALPHAS + b]      = alpha_out;
      out[OFF_ROT + 4 * b + 0] = qw;
      out[OFF_ROT + 4 * b + 1] = 0.0f;
      out[OFF_ROT + 4 * b + 2] = qy;
      out[OFF_ROT + 4 * b + 3] = 0.0f;
      out[OFF_SCALES + b]      = scale;
      out[OFF_DEPTHS + b]      = depth;
      out[OFF_C2D + 2 * b + 0] = cx;
      out[OFF_C2D + 2 * b + 1] = cy;
      out[OFF_TRANS + 3 * b + 0] = tx_;
      out[OFF_TRANS + 3 * b + 1] = ty_;
      out[OFF_TRANS + 3 * b + 2] = tz_;
      out[OFF_CLP + b]         = logf(pmax);

      float* par = Wf + 256 + rank * 8;
      par[0] = scale; par[1] = qw; par[2] = qy; par[3] = tx_;
      par[4] = ty_;   par[5] = tz_; par[6] = feff; par[7] = 0.0f;
      Wi[32 + rank] = b;
    }
    if (tid <= NC) {
      Wi[tid]      = scnt_sh[tid];
      Wi[16 + tid] = cts_sh[tid];
    }
  } else {
    // blocks 1..16: pack coeffs into bf16 B-fragments
    unsigned short* BPu = (unsigned short*)(Wf + 1280);
    int total = cts_sh[NC] * 1024;      // elements
    for (int g = (bx - 1) * 256 + tid; g < total; g += 16 * 256) {
      int t   = g >> 10;
      int r10 = g & 1023;
      int ks  = r10 >> 9;
      int li  = (r10 >> 3) & 63;
      int j   = r10 & 7;
      int col = li & 15, kg = li >> 4;
      int k   = ks * 32 + kg * 8 + j;
      int c = 0;
      while (!(t >= cts_sh[c] && t < cts_sh[c + 1])) ++c;
      int local_ct = t - cts_sh[c];
      int n_c = scnt_sh[c + 1] - scnt_sh[c];
      float val = 0.0f;
      if (col < 15) {
        int lr = col / 3, comp = col - 3 * lr;
        int lrec = local_ct * 5 + lr;
        if (lrec < n_c) {
          int bb = rb_sh[scnt_sh[c] + lrec];
          val = fc[((size_t)(bb * NC + c) * NK + k) * 3 + comp];
        }
      }
      BPu[(size_t)g] = f2bf(val);
    }
  }
}

// ---- kernel 2: per-class GEMM on matrix cores + transform + scatter ---------
// grid (256, 8): x = vertex super-tile (64 v), y = class. 4 waves/block,
// wave w owns rows v0 = bx*64 + w*16. Loops over the class's col-tiles.
__global__ __launch_bounds__(256) void verts_kernel(
    const float* __restrict__ basev,    // (C, V, 3)
    const float* __restrict__ basis,    // (C, V, K)
    const int*   __restrict__ Wi,
    const float* __restrict__ Wf,
    float* __restrict__ out) {
  int c   = blockIdx.y;
  int ct0 = Wi[16 + c], ct1 = Wi[16 + c + 1];
  if (ct0 >= ct1) return;
  int rec0  = Wi[c];
  int nrecs = Wi[c + 1] - rec0;

  int wave = threadIdx.x >> 6;
  int lane = threadIdx.x & 63;
  int v0   = blockIdx.x * 64 + wave * 16;
  int row  = lane & 15, kg = lane >> 4;

  // A fragments: basis[c][v0+row][k], k = ks*32 + kg*8 + j   (f32 -> bf16)
  const float* ab = basis + ((size_t)c * NV + (v0 + row)) * NK + kg * 8;
  float4 a0 = *(const float4*)(ab);
  float4 a1 = *(const float4*)(ab + 4);
  float4 a2 = *(const float4*)(ab + 32);
  float4 a3 = *(const float4*)(ab + 36);
  short8 A0, A1;
  A0[0]=f2bf(a0.x); A0[1]=f2bf(a0.y); A0[2]=f2bf(a0.z); A0[3]=f2bf(a0.w);
  A0[4]=f2bf(a1.x); A0[5]=f2bf(a1.y); A0[6]=f2bf(a1.z); A0[7]=f2bf(a1.w);
  A1[0]=f2bf(a2.x); A1[1]=f2bf(a2.y); A1[2]=f2bf(a2.z); A1[3]=f2bf(a2.w);
  A1[4]=f2bf(a3.x); A1[5]=f2bf(a3.y); A1[6]=f2bf(a3.z); A1[7]=f2bf(a3.w);

  // epilogue constants: this lane writes component `comp` of record `lr` for
  // vertices ve = v0 + rowg*4 + j  (C/D layout: col=lane&15, row=(lane>>4)*4+j)
  int q = lane & 15, rowg = lane >> 4;
  int lr = q / 3, comp = q - 3 * lr;
  bool qok = (q < 15);
  float bvx[4], bvy[4], bvz[4];
#pragma unroll
  for (int j = 0; j < 4; ++j) {
    const float* bp = basev + ((size_t)c * NV + (v0 + rowg * 4 + j)) * 3;
    bvx[j] = bp[0]; bvy[j] = bp[1]; bvz[j] = bp[2];
  }

  const float4* BP4 = (const float4*)(Wf + 1280);

  for (int t = ct0; t < ct1; ++t) {
    float4 rb0 = BP4[(size_t)(t * 2 + 0) * 64 + lane];
    float4 rb1 = BP4[(size_t)(t * 2 + 1) * 64 + lane];
    short8 B0 = *(short8*)&rb0;
    short8 B1 = *(short8*)&rb1;
    f32x4 acc = {0.0f, 0.0f, 0.0f, 0.0f};
    acc = __builtin_amdgcn_mfma_f32_16x16x32_bf16(A0, B0, acc, 0, 0, 0);
    acc = __builtin_amdgcn_mfma_f32_16x16x32_bf16(A1, B1, acc, 0, 0, 0);

    int nrec_ct = nrecs - (t - ct0) * 5;
    nrec_ct = (nrec_ct > 5) ? 5 : nrec_ct;
    bool valid = qok && (lr < nrec_ct);
    int rec = rec0 + (t - ct0) * 5 + (valid ? lr : 0);
    int bb  = Wi[32 + rec];
    float4 P0 = *(const float4*)(Wf + 256 + rec * 8);
    float4 P1 = *(const float4*)(Wf + 256 + rec * 8 + 4);
    float scale = P0.x, qw = P0.y, qy = P0.z, tx = P0.w;
    float ty = P1.x, tz = P1.y, feff = P1.z;
    int sbase = lane & 48;
    int sx = sbase | (qok ? 3 * lr     : 0);
    int sy = sbase | (qok ? 3 * lr + 1 : 0);
    int sz = sbase | (qok ? 3 * lr + 2 : 0);

#pragma unroll
    for (int j = 0; j < 4; ++j) {
      float dx_ = __shfl(acc[j], sx);
      float dy_ = __shfl(acc[j], sy);
      float dz_ = __shfl(acc[j], sz);
      int ve = v0 + rowg * 4 + j;

      float vx = (bvx[j] + dx_) * scale;
      float vy = (bvy[j] + dy_) * scale;
      float vz = (bvz[j] + dz_) * scale;
      float t2x = 2.0f * qy * vz;
      float t2z = -2.0f * qy * vx;
      float rx = vx + qw * t2x + qy * t2z;
      float ry = vy;
      float rz = vz + qw * t2z - qy * t2x;
      float wx = rx + tx, wy = ry + ty, wz = rz + tz;

      float zv = wz;
      float zsafe = (zv > -1e-4f) ? -1e-4f : zv;
      float inv = feff / (-zsafe);
      float px = (wx * inv * 0.5f + 0.5f) * (float)NR;
      float py = (wy * inv * 0.5f + 0.5f) * (float)NR;

      if (valid) {
        float ov = (comp == 0) ? px : ((comp == 1) ? py : -zv);
        out[OFF_VP + ((size_t)bb * NV + ve) * 3 + comp] = ov;
        if (comp == 0) {
          int xi = (int)fminf(fmaxf(px, 0.0f), 127.0f);
          int yi = (int)fminf(fmaxf(py, 0.0f), 127.0f);
          out[OFF_MASKS + (bb << 14) + yi * NR + xi] = 1.0f;
        }
      }
    }
  }
}

extern "C" void kernel_launch(void* const* d_in, const int* in_sizes, int n_in,
                              void* d_out, int out_size, void* d_ws, size_t ws_size,
                              hipStream_t stream) {
  const float* roi    = (const float*)d_in[0];
  const float* focals = (const float*)d_in[1];
  const float* td     = (const float*)d_in[2];
  const float* t2     = (const float*)d_in[3];
  const float* ls     = (const float*)d_in[4];
  const float* ld     = (const float*)d_in[5];
  const float* cp     = (const float*)d_in[6];
  const float* fc     = (const float*)d_in[7];
  const float* bv     = (const float*)d_in[8];
  const float* fb     = (const float*)d_in[9];
  float* out = (float*)d_out;
  int*   Wi  = (int*)d_ws;
  float* Wf  = (float*)d_ws;

  prep_kernel<<<dim3(2048), dim3(256), 0, stream>>>(
      roi, focals, td, t2, ls, ld, cp, fc, out, Wi, Wf);
  verts_kernel<<<dim3(256, 8), dim3(256), 0, stream>>>(
      bv, fb, Wi, Wf, out);
}